// Round 11
// baseline (372.586 us; speedup 1.0000x reference)
//
#include <hip/hip_runtime.h>
#include <hip/hip_bf16.h>
#include <cstdint>

// Problem: B=2, S=2048, D=2048, HQ=16, DH=128, single shared K/V head (GQA).
// Inputs/outputs fp32 (runtime-detected; flag in ws[0]); compute bf16 MFMA.

typedef __bf16 bf16;
typedef __bf16 bf16x8 __attribute__((ext_vector_type(8)));
typedef __bf16 bf16x4 __attribute__((ext_vector_type(4)));
typedef float  floatx4 __attribute__((ext_vector_type(4)));

__device__ __forceinline__ floatx4 mfma16(bf16x8 a, bf16x8 b, floatx4 c) {
  return __builtin_amdgcn_mfma_f32_16x16x32_bf16(a, b, c, 0, 0, 0);
}

__device__ __forceinline__ void glds16(const bf16* g, bf16* l) {
  __builtin_amdgcn_global_load_lds(
      (const __attribute__((address_space(1))) unsigned int*)(const void*)g,
      (__attribute__((address_space(3))) unsigned int*)(void*)l, 16, 0, 0);
}

// ---------------------------------------------------------------------------
// dtype probe + bias convert in one dispatch (single block)
// ---------------------------------------------------------------------------
__global__ void detect_bias_kernel(
    const unsigned short* __restrict__ xs, int* flag,
    const void* s0, const void* s1, const void* s2, const void* s3,
    bf16* d0, bf16* d1, bf16* d2, bf16* d3) {
  __shared__ int cnt;
  if (threadIdx.x == 0) cnt = 0;
  __syncthreads();
  int bad = 0;
  for (int i = threadIdx.x; i < 8192; i += 256) {
    const unsigned e = (xs[i] >> 7) & 0xFF;
    if (e >= 0x90 || e <= 0x5F) bad++;
  }
  atomicAdd(&cnt, bad);
  __syncthreads();
  const int f = (cnt > 256) ? 1 : 0;
  if (threadIdx.x == 0) *flag = f;
  const void* ss[4] = {s0, s1, s2, s3};
  bf16* dd[4] = {d0, d1, d2, d3};
  const int nn[4] = {2048, 128, 128, 2048};
#pragma unroll
  for (int a = 0; a < 4; ++a)
    for (int i = threadIdx.x; i < nn[a]; i += 256)
      dd[a][i] = f ? (bf16)((const float*)ss[a])[i] : ((const bf16*)ss[a])[i];
}

// vectorized convert-or-copy, 4 elems/thread/step
__global__ __launch_bounds__(256) void convertv_kernel(
    const void* __restrict__ src, bf16* __restrict__ dst, int n4,
    const int* __restrict__ flag) {
  const int f = *flag;
  int i = blockIdx.x * 256 + threadIdx.x;
  const int stride = gridDim.x * 256;
  if (f) {
    const float4* s = (const float4*)src;
    for (; i < n4; i += stride) {
      const float4 v = s[i];
      bf16x4 o = {(bf16)v.x, (bf16)v.y, (bf16)v.z, (bf16)v.w};
      *(bf16x4*)(dst + (size_t)i * 4) = o;
    }
  } else {
    const ushort4* s = (const ushort4*)src;
    for (; i < n4; i += stride) ((ushort4*)dst)[i] = s[i];
  }
}

// two transposes+converts in one dispatch (blockIdx.z selects pair member)
__global__ __launch_bounds__(256) void convt2_kernel(
    const void* __restrict__ srcA, const void* __restrict__ srcB,
    bf16* __restrict__ dstA, bf16* __restrict__ dstB, int R, int C,
    const int* __restrict__ flag) {
  __shared__ bf16 tile[32][33];
  const void* src = blockIdx.z ? srcB : srcA;
  bf16* dst = blockIdx.z ? dstB : dstA;
  const int f = *flag;
  const int tx = threadIdx.x & 31, ty = threadIdx.x >> 5;
  const int bx = blockIdx.x * 32, by = blockIdx.y * 32;
  if (f) {
    const float* s = (const float*)src;
#pragma unroll
    for (int i = 0; i < 32; i += 8)
      tile[ty + i][tx] = (bf16)s[(size_t)(by + ty + i) * C + bx + tx];
  } else {
    const bf16* s = (const bf16*)src;
#pragma unroll
    for (int i = 0; i < 32; i += 8)
      tile[ty + i][tx] = s[(size_t)(by + ty + i) * C + bx + tx];
  }
  __syncthreads();
#pragma unroll
  for (int i = 0; i < 32; i += 8)
    dst[(size_t)(bx + ty + i) * R + by + tx] = tile[tx][ty + i];
}

// bf16 strided transpose + kv-permute: out[c][perm(r)] = in[r*2304 + c].
// Within each 32-token group, token kv = 16h+4q+r is stored at position
// 8q+4h+r (flash's permuted-kv PV mapping; O is kv-sum-invariant). Verified
// on HW rounds 6-10 (passed, absmax unchanged).
__global__ __launch_bounds__(256) void transv_kernel(
    const bf16* __restrict__ in, bf16* __restrict__ out) {
  __shared__ bf16 tile[32][33];
  const int tx = threadIdx.x & 31, ty = threadIdx.x >> 5;
  const int bx = blockIdx.x * 32, by = blockIdx.y * 32;
#pragma unroll
  for (int i = 0; i < 32; i += 8)
    tile[ty + i][tx] = in[(size_t)(by + ty + i) * 2304 + bx + tx];
  __syncthreads();
  const int txp = ((tx >> 2) & 3) * 8 + ((tx >> 4) & 1) * 4 + (tx & 3);
#pragma unroll
  for (int i = 0; i < 32; i += 8)
    out[(size_t)(bx + ty + i) * 4096 + by + txp] = tile[tx][ty + i];
}

// ---------------------------------------------------------------------------
// C[M][N] = A[M][K] @ Bt[N][K]^T (+bias). m97 128x128 tile, BK=32, 4 waves.
// REVERTED to round-9 exact (measured best 311.9): round-10's explicit DMA
// double-buffer was flat — at 4 blocks/CU the inter-block overlap already
// hides the per-iter drain (m99/m100 mechanism). Kept from round 9:
// __launch_bounds__(256,4) and the bijective XCD-chunked swizzle.
// ---------------------------------------------------------------------------
__global__ __launch_bounds__(256, 4) void gemm_bt_kernel(
    const bf16* __restrict__ A, const bf16* __restrict__ Bt,
    const bf16* __restrict__ bias, void* __restrict__ Cout,
    const int M, const int N, const int K, const int bias_mode,
    const int* __restrict__ f32out) {
  __shared__ __align__(16) bf16 ldsA[128 * 32];
  __shared__ __align__(16) bf16 ldsB[128 * 32];
  const int tid = threadIdx.x, lane = tid & 63, wave = tid >> 6;
  const int l15 = lane & 15, quad = lane >> 4;

  // XCD-chunked bijective swizzle (nwg % 8 == 0 for both call sites)
  const int nwg = gridDim.x * gridDim.y;
  int bid = blockIdx.y * gridDim.x + blockIdx.x;
  bid = (bid & 7) * (nwg >> 3) + (bid >> 3);
  const int m0 = (bid / gridDim.x) * 128, n0 = (bid % gridDim.x) * 128;

  const int wm = wave >> 1, wn = wave & 1;
  const int f32 = f32out ? *f32out : 0;

  floatx4 acc[4][4];
  const floatx4 z4 = {0.f, 0.f, 0.f, 0.f};
#pragma unroll
  for (int i = 0; i < 4; ++i)
#pragma unroll
    for (int j = 0; j < 4; ++j) acc[i][j] = z4;

  const int srow = (lane >> 2);
  const int scol = (lane & 3) * 8;

  for (int k0 = 0; k0 < K; k0 += 32) {
    __syncthreads();
#pragma unroll
    for (int j = 0; j < 2; ++j) {
      const int chunk = wave * 2 + j;
      glds16(A + (size_t)(m0 + chunk * 16 + srow) * K + k0 + scol, ldsA + chunk * 512);
      glds16(Bt + (size_t)(n0 + chunk * 16 + srow) * K + k0 + scol, ldsB + chunk * 512);
    }
    __syncthreads();
    bf16x8 af[4], bfr[4];
#pragma unroll
    for (int i = 0; i < 4; ++i) {
      af[i]  = *(const bf16x8*)(ldsA + (wm * 64 + i * 16 + l15) * 32 + quad * 8);
      bfr[i] = *(const bf16x8*)(ldsB + (wn * 64 + i * 16 + l15) * 32 + quad * 8);
    }
#pragma unroll
    for (int mi = 0; mi < 4; ++mi)
#pragma unroll
      for (int ni = 0; ni < 4; ++ni)
        acc[mi][ni] = mfma16(af[mi], bfr[ni], acc[mi][ni]);
  }

#pragma unroll
  for (int mi = 0; mi < 4; ++mi) {
    const int row0 = m0 + wm * 64 + mi * 16 + quad * 4;
#pragma unroll
    for (int ni = 0; ni < 4; ++ni) {
      const int col = n0 + wn * 64 + ni * 16 + l15;
      const float badd = (bias_mode == 1) ? (float)bias[col] : 0.f;
#pragma unroll
      for (int r = 0; r < 4; ++r) {
        float v = acc[mi][ni][r] + badd;
        if (bias_mode == 2) v += (float)bias[row0 + r];
        const size_t idx = (size_t)(row0 + r) * N + col;
        if (f32) ((float*)Cout)[idx] = v;
        else     ((bf16*)Cout)[idx]  = (bf16)v;
      }
    }
  }
}

// ---------------------------------------------------------------------------
// Flash attention v12 — v11 + GLOBAL-DIRECT V (v5's idea with correct vmcnt
// ordering). Round-7 diagnosis: CU-shared LDS pipe is the wall; round-8
// (-ds_writes) confirmed. Now the 16 vf LDS reads go too: VTg is 1MB,
// kv-permuted (v10), L2-resident per XCD; vf = bf16x8 at
// vtb + d*4096 + kvn + kf2*32 + quad*8 — algebraically identical to v11's
// LDS read (slot gp^(d&7) of a s^(d&7)-staged buffer = granule gp).
// Why v5's trap doesn't apply: staging is DMA-only (no register-destined
// VMEM crosses an iteration). vf loads are issued at iter TOP right after
// the K-DMAs; PV's vmcnt wait forces the 4 older K-DMAs complete first —
// harmless (issued ~1500cyc earlier, only needed by the bottom barrier).
// Per wave-iter: LDS ops 32 -> 16 (af only). VT staging deleted.
// LDS: K dbuf 2x16K = 32 KB. VGPR ~150 (vf[2][8] held across QK).
// ---------------------------------------------------------------------------
__global__ __launch_bounds__(256, 2) void flash_kernel(
    const bf16* __restrict__ Cqkv,  // [4096][2304]  Q cols 0..2047, K cols 2048..2175
    const bf16* __restrict__ VTg,   // [128][4096] kv-permuted (see transv)
    bf16* __restrict__ Og) {        // [4096][2048]
  __shared__ __align__(16) bf16 ldsK[16384];  // 32 KB: [2][64 kv][128 d], slot g^(row&15)

  const int tid = threadIdx.x, lane = tid & 63, wave = tid >> 6;
  const int l15 = lane & 15, quad = lane >> 4;
  const int qb = blockIdx.x, bh = blockIdx.y;
  const int b = bh >> 4, h = bh & 15;

  // ---- Q fragments direct from global (one-time; B-op: n=l15, k=quad*8+j) ----
  bf16x8 qfrag[2][4];
  {
    const bf16* qbase = Cqkv + (size_t)(b * 2048 + qb * 128 + wave * 32) * 2304 + h * 128;
#pragma unroll
    for (int qi = 0; qi < 2; ++qi)
#pragma unroll
      for (int kf = 0; kf < 4; ++kf)
        qfrag[qi][kf] =
            *(const bf16x8*)(qbase + (size_t)(qi * 16 + l15) * 2304 + kf * 32 + quad * 8);
  }

  const bf16* kb  = Cqkv + 2048 + (size_t)(b * 2048) * 2304;
  const bf16* vtb = VTg + (size_t)b * 2048;

  // K staging geometry: 16 chunks (1 KB each), wave DMAs 4. LDS dest linear;
  // XOR swizzle in the per-lane global source (m173 pattern).
  int rK[4], gK[4];
#pragma unroll
  for (int j = 0; j < 4; ++j) {
    const int c = wave * 4 + j;
    rK[j] = c * 4 + quad;
    gK[j] = l15 ^ (rK[j] & 15);
  }

  // ---- prologue: DMA K tile 0 into buffer 0, publish ----
#pragma unroll
  for (int j = 0; j < 4; ++j)
    glds16(kb + (size_t)rK[j] * 2304 + gK[j] * 8, ldsK + (wave * 4 + j) * 512);
  asm volatile("s_waitcnt vmcnt(0)\n\ts_barrier" ::: "memory");

  floatx4 oacc[2][8];
  const floatx4 z4 = {0.f, 0.f, 0.f, 0.f};
#pragma unroll
  for (int mi = 0; mi < 2; ++mi)
#pragma unroll
    for (int ni = 0; ni < 8; ++ni) oacc[mi][ni] = z4;
  float lrun[2] = {0.f, 0.f};
  const float c1  = 0.12751745f;  // (1/sqrt(128)) * log2(e)
  const float mu2 = 4.3280850f;   // 3 * log2(e)

  for (int it = 0; it < 32; ++it) {
    const int kvn = it * 64;
    const bf16* kcur = ldsK + (it & 1) * 8192;

    // ---- DMA K tile it+1 into the other buffer at iter TOP ----
    if (it < 31) {
      bf16* knext = ldsK + ((it + 1) & 1) * 8192;
#pragma unroll
      for (int j = 0; j < 4; ++j)
        glds16(kb + (size_t)(kvn + 64 + rK[j]) * 2304 + gK[j] * 8,
               knext + (wave * 4 + j) * 512);
    }

    // ---- vf for THIS iter: global-direct from permuted VTg (L2-resident) ----
    // Issued here (~1500cyc before PV consumes). PV's wait also drains the
    // older K-DMAs — they're done by then; harmless.
    bf16x8 vf[2][8];
#pragma unroll
    for (int kf2 = 0; kf2 < 2; ++kf2)
#pragma unroll
      for (int ni = 0; ni < 8; ++ni)
        vf[kf2][ni] = *(const bf16x8*)(vtb + (size_t)(ni * 16 + l15) * 4096 +
                                       kvn + kf2 * 32 + quad * 8);

    // ---- S^T = K.Q^T : D[m=kv 64][n=q 16] x2 qi; af reused across qi ----
    floatx4 sacc[4][2];
#pragma unroll
    for (int kvi = 0; kvi < 4; ++kvi) { sacc[kvi][0] = z4; sacc[kvi][1] = z4; }
    __builtin_amdgcn_s_setprio(1);
#pragma unroll
    for (int kf = 0; kf < 4; ++kf) {
      const int gg = (kf * 4 + quad) ^ l15;
#pragma unroll
      for (int kvi = 0; kvi < 4; ++kvi) {
        bf16x8 af = *(const bf16x8*)(kcur + (kvi * 16 + l15) * 128 + gg * 8);
        sacc[kvi][0] = mfma16(af, qfrag[0][kf], sacc[kvi][0]);
        sacc[kvi][1] = mfma16(af, qfrag[1][kf], sacc[kvi][1]);
      }
    }
    __builtin_amdgcn_s_setprio(0);

    // ---- P = exp2(s*c1 - mu2): bf16x4 per (qi,kvi), kept in REGISTERS ----
    bf16x4 pv[2][4];
    float rs[2] = {0.f, 0.f};
#pragma unroll
    for (int qi = 0; qi < 2; ++qi) {
#pragma unroll
      for (int kvi = 0; kvi < 4; ++kvi) {
#pragma unroll
        for (int r = 0; r < 4; ++r) {
          const float p = __builtin_amdgcn_exp2f(fmaf(sacc[kvi][qi][r], c1, -mu2));
          rs[qi] += p;
          pv[qi][kvi][r] = (bf16)p;
        }
      }
    }
#pragma unroll
    for (int qi = 0; qi < 2; ++qi) {
      float r2 = rs[qi];
      r2 += __shfl_xor(r2, 16);
      r2 += __shfl_xor(r2, 32);
      lrun[qi] += r2;
    }

    // ---- O += P.V ; P lane-local (permuted-kv), V from registers ----
    __builtin_amdgcn_s_setprio(1);
#pragma unroll
    for (int kf2 = 0; kf2 < 2; ++kf2) {
      const bf16x8 pf0 = __builtin_shufflevector(pv[0][kf2 * 2], pv[0][kf2 * 2 + 1],
                                                 0, 1, 2, 3, 4, 5, 6, 7);
      const bf16x8 pf1 = __builtin_shufflevector(pv[1][kf2 * 2], pv[1][kf2 * 2 + 1],
                                                 0, 1, 2, 3, 4, 5, 6, 7);
#pragma unroll
      for (int ni = 0; ni < 8; ++ni) {
        oacc[0][ni] = mfma16(pf0, vf[kf2][ni], oacc[0][ni]);
        oacc[1][ni] = mfma16(pf1, vf[kf2][ni], oacc[1][ni]);
      }
    }
    __builtin_amdgcn_s_setprio(0);

    // ---- bottom barrier: K DMA it+1 landed + my af reads of tile it done ----
    if (it < 31)
      asm volatile("s_waitcnt vmcnt(0) lgkmcnt(0)\n\ts_barrier" ::: "memory");
  }

  // ---- epilogue: O / l ----
#pragma unroll
  for (int mi = 0; mi < 2; ++mi) {
    float inv[4];
#pragma unroll
    for (int r = 0; r < 4; ++r) inv[r] = 1.0f / __shfl(lrun[mi], quad * 4 + r);
    const size_t row0 = (size_t)(b * 2048 + qb * 128 + wave * 32 + mi * 16 + quad * 4);
#pragma unroll
    for (int ni = 0; ni < 8; ++ni) {
      const size_t base = row0 * 2048 + h * 128 + ni * 16 + l15;
#pragma unroll
      for (int r = 0; r < 4; ++r)
        Og[base + (size_t)r * 2048] = (bf16)(oacc[mi][ni][r] * inv[r]);
    }
  }
}

// ---------------------------------------------------------------------------
extern "C" void kernel_launch(void* const* d_in, const int* in_sizes, int n_in,
                              void* d_out, int out_size, void* d_ws, size_t ws_size,
                              hipStream_t stream) {
  (void)in_sizes; (void)n_in; (void)out_size; (void)ws_size;
  char* ws = (char*)d_ws;
  int*  flag   = (int*)ws;                    // [0,1024)
  bf16* x_c    = (bf16*)(ws + 1024);          // 16 MB; Og overlays (last x_c read
  bf16* Og     = x_c;                         //   is several dispatches earlier)
  bf16* WqkvT  = (bf16*)(ws + 16778240);      // [2304][2048] 9.4 MB
  bf16* WoT    = (bf16*)(ws + 26215424);      // [2048][2048] 8 MB
  bf16* bqkv   = (bf16*)(ws + 34604032);      // [2304]
  bf16* bo_c   = (bf16*)(ws + 34609152);      // [2048]
  bf16* Cqkv   = (bf16*)(ws + 34614272);      // [4096][2304] 18.9 MB -> 53488640
  bf16* VTg    = (bf16*)(ws + 53489664);      // [128][4096] 1 MB (kv-permuted)

  const dim3 blk(256);
  // dtype probe + bias conversion (one block)
  detect_bias_kernel<<<1, blk, 0, stream>>>(
      (const unsigned short*)d_in[0], flag, d_in[2], d_in[4], d_in[6], d_in[8],
      bqkv, bqkv + 2048, bqkv + 2176, bo_c);

  convertv_kernel<<<dim3(2048), blk, 0, stream>>>(d_in[0], x_c, (4096 * 2048) / 4, flag);
  // WqkvT rows: [0,2048)=Wq^T, [2048,2176)=Wk^T, [2176,2304)=Wv^T
  convt2_kernel<<<dim3(64, 64, 2), blk, 0, stream>>>(d_in[1], d_in[7], WqkvT, WoT,
                                                     2048, 2048, flag);
  convt2_kernel<<<dim3(4, 64, 2), blk, 0, stream>>>(d_in[3], d_in[5],
                                                    WqkvT + 2048 * 2048,
                                                    WqkvT + 2176 * 2048,
                                                    2048, 128, flag);

  // QKV = x @ [Wq|Wk|Wv] + [bq|bk|bv] : [4096][2304]
  gemm_bt_kernel<<<dim3(18, 32), blk, 0, stream>>>(x_c, WqkvT, bqkv, Cqkv,
                                                   4096, 2304, 2048, 1, nullptr);
  // V^T (kv-permuted): [128][4096] from Cqkv cols [2176,2304)
  transv_kernel<<<dim3(4, 128), blk, 0, stream>>>(Cqkv + 2176, VTg);
  // attention
  flash_kernel<<<dim3(16, 32), blk, 0, stream>>>(Cqkv, VTg, Og);
  // out = Og@Wo + bo (fp32 store per flag)
  gemm_bt_kernel<<<dim3(16, 32), blk, 0, stream>>>(Og, WoT, bo_c, d_out,
                                                   4096, 2048, 2048, 1, flag);
}

// Round 12
// 309.774 us; speedup vs baseline: 1.2028x; 1.2028x over previous
//
#include <hip/hip_runtime.h>
#include <hip/hip_bf16.h>
#include <cstdint>

// Problem: B=2, S=2048, D=2048, HQ=16, DH=128, single shared K/V head (GQA).
// Inputs/outputs fp32 (runtime-detected; flag in ws[0]); compute bf16 MFMA.

typedef __bf16 bf16;
typedef __bf16 bf16x8 __attribute__((ext_vector_type(8)));
typedef __bf16 bf16x4 __attribute__((ext_vector_type(4)));
typedef float  floatx4 __attribute__((ext_vector_type(4)));

__device__ __forceinline__ floatx4 mfma16(bf16x8 a, bf16x8 b, floatx4 c) {
  return __builtin_amdgcn_mfma_f32_16x16x32_bf16(a, b, c, 0, 0, 0);
}

__device__ __forceinline__ void glds16(const bf16* g, bf16* l) {
  __builtin_amdgcn_global_load_lds(
      (const __attribute__((address_space(1))) unsigned int*)(const void*)g,
      (__attribute__((address_space(3))) unsigned int*)(void*)l, 16, 0, 0);
}

// ---------------------------------------------------------------------------
// dtype probe + bias convert in one dispatch (single block)
// ---------------------------------------------------------------------------
__global__ void detect_bias_kernel(
    const unsigned short* __restrict__ xs, int* flag,
    const void* s0, const void* s1, const void* s2, const void* s3,
    bf16* d0, bf16* d1, bf16* d2, bf16* d3) {
  __shared__ int cnt;
  if (threadIdx.x == 0) cnt = 0;
  __syncthreads();
  int bad = 0;
  for (int i = threadIdx.x; i < 8192; i += 256) {
    const unsigned e = (xs[i] >> 7) & 0xFF;
    if (e >= 0x90 || e <= 0x5F) bad++;
  }
  atomicAdd(&cnt, bad);
  __syncthreads();
  const int f = (cnt > 256) ? 1 : 0;
  if (threadIdx.x == 0) *flag = f;
  const void* ss[4] = {s0, s1, s2, s3};
  bf16* dd[4] = {d0, d1, d2, d3};
  const int nn[4] = {2048, 128, 128, 2048};
#pragma unroll
  for (int a = 0; a < 4; ++a)
    for (int i = threadIdx.x; i < nn[a]; i += 256)
      dd[a][i] = f ? (bf16)((const float*)ss[a])[i] : ((const bf16*)ss[a])[i];
}

// vectorized convert-or-copy, 4 elems/thread/step
__global__ __launch_bounds__(256) void convertv_kernel(
    const void* __restrict__ src, bf16* __restrict__ dst, int n4,
    const int* __restrict__ flag) {
  const int f = *flag;
  int i = blockIdx.x * 256 + threadIdx.x;
  const int stride = gridDim.x * 256;
  if (f) {
    const float4* s = (const float4*)src;
    for (; i < n4; i += stride) {
      const float4 v = s[i];
      bf16x4 o = {(bf16)v.x, (bf16)v.y, (bf16)v.z, (bf16)v.w};
      *(bf16x4*)(dst + (size_t)i * 4) = o;
    }
  } else {
    const ushort4* s = (const ushort4*)src;
    for (; i < n4; i += stride) ((ushort4*)dst)[i] = s[i];
  }
}

// ---------------------------------------------------------------------------
// FOUR transposes+converts in ONE dispatch (round-12 fusion; was 2 dispatches).
// grid (68,64,2): bx<64 -> big pair (Wq->WqkvT / Wo->WoT, C=2048);
// bx>=64 -> small pair (Wk->WqkvT+2048*2048 / Wv->WqkvT+2176*2048, C=128).
// R=2048 (dst row stride) for all four.
// ---------------------------------------------------------------------------
__global__ __launch_bounds__(256) void convt4_kernel(
    const void* __restrict__ sWq, const void* __restrict__ sWo,
    const void* __restrict__ sWk, const void* __restrict__ sWv,
    bf16* __restrict__ dWq, bf16* __restrict__ dWo,
    bf16* __restrict__ dWk, bf16* __restrict__ dWv,
    const int* __restrict__ flag) {
  __shared__ bf16 tile[32][33];
  const int zz = blockIdx.z;
  const bool big = (blockIdx.x < 64);
  const void* src = big ? (zz ? sWo : sWq) : (zz ? sWv : sWk);
  bf16* dst       = big ? (zz ? dWo : dWq) : (zz ? dWv : dWk);
  const int C = big ? 2048 : 128;
  const int f = *flag;
  const int tx = threadIdx.x & 31, ty = threadIdx.x >> 5;
  const int bx = (big ? blockIdx.x : blockIdx.x - 64) * 32;
  const int by = blockIdx.y * 32;
  if (f) {
    const float* s = (const float*)src;
#pragma unroll
    for (int i = 0; i < 32; i += 8)
      tile[ty + i][tx] = (bf16)s[(size_t)(by + ty + i) * C + bx + tx];
  } else {
    const bf16* s = (const bf16*)src;
#pragma unroll
    for (int i = 0; i < 32; i += 8)
      tile[ty + i][tx] = s[(size_t)(by + ty + i) * C + bx + tx];
  }
  __syncthreads();
#pragma unroll
  for (int i = 0; i < 32; i += 8)
    dst[(size_t)(bx + ty + i) * 2048 + by + tx] = tile[tx][ty + i];
}

// ---------------------------------------------------------------------------
// C[M][N] = A[M][K] @ Bt[N][K]^T (+bias). m97 128x128 tile, BK=32, 4 waves.
// Round-9 config (measured best): __launch_bounds__(256,4) + bijective
// XCD-chunked swizzle. Round-10's explicit dbuf was flat (4-block overlap
// already hides the drain) — not re-applied.
// Round-12: optional fused V^T-permuted side-write (vtg != nullptr, gemm1
// only). Blocks whose cols land in [2176,2304) also store their acc values
// to VTg in the flash kv-permuted layout: within a 32-row group,
// o=(mi&1)*16+quad*4+r  ->  perm position 8*quad+4*(mi&1)+r, so the 4
// r-values form one contiguous bf16x4 at
//   VTg[(col-2176)*4096 + (row0&~31) + 8*quad + 4*(mi&1)].
// Bit-identical to the old transv pass (same bf16 rounding of the same v).
// ---------------------------------------------------------------------------
__global__ __launch_bounds__(256, 4) void gemm_bt_kernel(
    const bf16* __restrict__ A, const bf16* __restrict__ Bt,
    const bf16* __restrict__ bias, void* __restrict__ Cout,
    const int M, const int N, const int K, const int bias_mode,
    const int* __restrict__ f32out, bf16* __restrict__ vtg) {
  __shared__ __align__(16) bf16 ldsA[128 * 32];
  __shared__ __align__(16) bf16 ldsB[128 * 32];
  const int tid = threadIdx.x, lane = tid & 63, wave = tid >> 6;
  const int l15 = lane & 15, quad = lane >> 4;

  // XCD-chunked bijective swizzle (nwg % 8 == 0 for both call sites)
  const int nwg = gridDim.x * gridDim.y;
  int bid = blockIdx.y * gridDim.x + blockIdx.x;
  bid = (bid & 7) * (nwg >> 3) + (bid >> 3);
  const int m0 = (bid / gridDim.x) * 128, n0 = (bid % gridDim.x) * 128;

  const int wm = wave >> 1, wn = wave & 1;
  const int f32 = f32out ? *f32out : 0;

  floatx4 acc[4][4];
  const floatx4 z4 = {0.f, 0.f, 0.f, 0.f};
#pragma unroll
  for (int i = 0; i < 4; ++i)
#pragma unroll
    for (int j = 0; j < 4; ++j) acc[i][j] = z4;

  const int srow = (lane >> 2);
  const int scol = (lane & 3) * 8;

  for (int k0 = 0; k0 < K; k0 += 32) {
    __syncthreads();
#pragma unroll
    for (int j = 0; j < 2; ++j) {
      const int chunk = wave * 2 + j;
      glds16(A + (size_t)(m0 + chunk * 16 + srow) * K + k0 + scol, ldsA + chunk * 512);
      glds16(Bt + (size_t)(n0 + chunk * 16 + srow) * K + k0 + scol, ldsB + chunk * 512);
    }
    __syncthreads();
    bf16x8 af[4], bfr[4];
#pragma unroll
    for (int i = 0; i < 4; ++i) {
      af[i]  = *(const bf16x8*)(ldsA + (wm * 64 + i * 16 + l15) * 32 + quad * 8);
      bfr[i] = *(const bf16x8*)(ldsB + (wn * 64 + i * 16 + l15) * 32 + quad * 8);
    }
#pragma unroll
    for (int mi = 0; mi < 4; ++mi)
#pragma unroll
      for (int ni = 0; ni < 4; ++ni)
        acc[mi][ni] = mfma16(af[mi], bfr[ni], acc[mi][ni]);
  }

#pragma unroll
  for (int mi = 0; mi < 4; ++mi) {
    const int row0 = m0 + wm * 64 + mi * 16 + quad * 4;
#pragma unroll
    for (int ni = 0; ni < 4; ++ni) {
      const int col = n0 + wn * 64 + ni * 16 + l15;
      const float badd = (bias_mode == 1) ? (float)bias[col] : 0.f;
      bf16x4 v4;
#pragma unroll
      for (int r = 0; r < 4; ++r) {
        float v = acc[mi][ni][r] + badd;
        if (bias_mode == 2) v += (float)bias[row0 + r];
        const size_t idx = (size_t)(row0 + r) * N + col;
        if (f32) ((float*)Cout)[idx] = v;
        else     ((bf16*)Cout)[idx]  = (bf16)v;
        v4[r] = (bf16)v;
      }
      if (vtg && col >= 2176)
        *(bf16x4*)(vtg + (size_t)(col - 2176) * 4096 + (row0 & ~31) +
                   8 * quad + 4 * (mi & 1)) = v4;
    }
  }
}

// ---------------------------------------------------------------------------
// Flash attention v11 — REVERTED (round-11's global-direct V hit the L2
// request-rate wall: per-wave 16-segment gathers vs once-per-block DMA = 8x
// L2 request traffic; 140us, same signature as v5). v11 measured 79.3-79.5us,
// MfmaUtil 36, conflicts 0, VGPR 92 — the plateau for this decomposition.
// Structure: K+VT double-buffered in LDS via global_load_lds DMA (linear
// dest, XOR-swizzled per-lane global source, m173 pattern); in-register P
// (permuted-kv, v10); single vmcnt(0)+lgkm(0)+barrier per iteration.
// ---------------------------------------------------------------------------
__global__ __launch_bounds__(256, 2) void flash_kernel(
    const bf16* __restrict__ Cqkv,  // [4096][2304]  Q cols 0..2047, K cols 2048..2175
    const bf16* __restrict__ VTg,   // [128][4096] kv-permuted
    bf16* __restrict__ Og) {        // [4096][2048]
  __shared__ __align__(16) bf16 lds_all[32768];  // 64 KB
  bf16* ldsK  = lds_all;           // [2][64 kv][128 d], granule slot = g ^ (row&15)
  bf16* ldsVT = lds_all + 16384;   // [2][128 d][64 kv'], granule slot = g ^ (d&7)

  const int tid = threadIdx.x, lane = tid & 63, wave = tid >> 6;
  const int l15 = lane & 15, quad = lane >> 4;
  const int qb = blockIdx.x, bh = blockIdx.y;
  const int b = bh >> 4, h = bh & 15;

  // ---- Q fragments direct from global (one-time; B-op: n=l15, k=quad*8+j) ----
  bf16x8 qfrag[2][4];
  {
    const bf16* qbase = Cqkv + (size_t)(b * 2048 + qb * 128 + wave * 32) * 2304 + h * 128;
#pragma unroll
    for (int qi = 0; qi < 2; ++qi)
#pragma unroll
      for (int kf = 0; kf < 4; ++kf)
        qfrag[qi][kf] =
            *(const bf16x8*)(qbase + (size_t)(qi * 16 + l15) * 2304 + kf * 32 + quad * 8);
  }

  const bf16* kb  = Cqkv + 2048 + (size_t)(b * 2048) * 2304;
  const bf16* vtb = VTg + (size_t)b * 2048;

  // staging geometry: 16 K-chunks + 16 VT-chunks (1 KB each), wave DMAs 4+4.
  int rK[4], gK[4], dV[4], gV[4];
#pragma unroll
  for (int j = 0; j < 4; ++j) {
    const int c = wave * 4 + j;
    rK[j] = c * 4 + quad;          gK[j] = l15 ^ (rK[j] & 15);
    dV[j] = c * 8 + (lane >> 3);   gV[j] = (lane & 7) ^ (dV[j] & 7);
  }

  // ---- prologue: DMA tile 0 into buffer 0, publish ----
#pragma unroll
  for (int j = 0; j < 4; ++j) {
    const int c = wave * 4 + j;
    glds16(kb + (size_t)rK[j] * 2304 + gK[j] * 8, ldsK + c * 512);
    glds16(vtb + (size_t)dV[j] * 4096 + gV[j] * 8, ldsVT + c * 512);
  }
  asm volatile("s_waitcnt vmcnt(0)\n\ts_barrier" ::: "memory");

  floatx4 oacc[2][8];
  const floatx4 z4 = {0.f, 0.f, 0.f, 0.f};
#pragma unroll
  for (int mi = 0; mi < 2; ++mi)
#pragma unroll
    for (int ni = 0; ni < 8; ++ni) oacc[mi][ni] = z4;
  float lrun[2] = {0.f, 0.f};
  const float c1  = 0.12751745f;  // (1/sqrt(128)) * log2(e)
  const float mu2 = 4.3280850f;   // 3 * log2(e)

  for (int it = 0; it < 32; ++it) {
    const bf16* kcur  = ldsK  + (it & 1) * 8192;
    const bf16* vtcur = ldsVT + (it & 1) * 8192;

    // ---- DMA tile it+1 into the other buffers at iter TOP ----
    if (it < 31) {
      const int kvn = (it + 1) * 64;
      bf16* knext  = ldsK  + ((it + 1) & 1) * 8192;
      bf16* vtnext = ldsVT + ((it + 1) & 1) * 8192;
#pragma unroll
      for (int j = 0; j < 4; ++j) {
        const int c = wave * 4 + j;
        glds16(kb + (size_t)(kvn + rK[j]) * 2304 + gK[j] * 8, knext + c * 512);
        glds16(vtb + (size_t)dV[j] * 4096 + kvn + gV[j] * 8, vtnext + c * 512);
      }
    }

    // ---- S^T = K.Q^T : D[m=kv 64][n=q 16] x2 qi; af reused across qi ----
    floatx4 sacc[4][2];
#pragma unroll
    for (int kvi = 0; kvi < 4; ++kvi) { sacc[kvi][0] = z4; sacc[kvi][1] = z4; }
    __builtin_amdgcn_s_setprio(1);
#pragma unroll
    for (int kf = 0; kf < 4; ++kf) {
      const int gg = (kf * 4 + quad) ^ l15;
#pragma unroll
      for (int kvi = 0; kvi < 4; ++kvi) {
        bf16x8 af = *(const bf16x8*)(kcur + (kvi * 16 + l15) * 128 + gg * 8);
        sacc[kvi][0] = mfma16(af, qfrag[0][kf], sacc[kvi][0]);
        sacc[kvi][1] = mfma16(af, qfrag[1][kf], sacc[kvi][1]);
      }
    }
    __builtin_amdgcn_s_setprio(0);

    // ---- P = exp2(s*c1 - mu2): bf16x4 per (qi,kvi), kept in REGISTERS ----
    bf16x4 pv[2][4];
    float rs[2] = {0.f, 0.f};
#pragma unroll
    for (int qi = 0; qi < 2; ++qi) {
#pragma unroll
      for (int kvi = 0; kvi < 4; ++kvi) {
#pragma unroll
        for (int r = 0; r < 4; ++r) {
          const float p = __builtin_amdgcn_exp2f(fmaf(sacc[kvi][qi][r], c1, -mu2));
          rs[qi] += p;
          pv[qi][kvi][r] = (bf16)p;
        }
      }
    }
#pragma unroll
    for (int qi = 0; qi < 2; ++qi) {
      float r2 = rs[qi];
      r2 += __shfl_xor(r2, 16);
      r2 += __shfl_xor(r2, 32);
      lrun[qi] += r2;
    }

    // ---- O += P.V ; P lane-local, V stored permuted -> single b128 reads ----
    __builtin_amdgcn_s_setprio(1);
#pragma unroll
    for (int kf2 = 0; kf2 < 2; ++kf2) {
      const bf16x8 pf0 = __builtin_shufflevector(pv[0][kf2 * 2], pv[0][kf2 * 2 + 1],
                                                 0, 1, 2, 3, 4, 5, 6, 7);
      const bf16x8 pf1 = __builtin_shufflevector(pv[1][kf2 * 2], pv[1][kf2 * 2 + 1],
                                                 0, 1, 2, 3, 4, 5, 6, 7);
      const int gp = kf2 * 4 + quad;  // granule of permuted kv' = 32*kf2+8*quad
#pragma unroll
      for (int ni = 0; ni < 8; ++ni) {
        const int d = ni * 16 + l15;
        const bf16x8 vf =
            *(const bf16x8*)(vtcur + d * 64 + ((gp ^ (l15 & 7)) << 3));
        oacc[0][ni] = mfma16(pf0, vf, oacc[0][ni]);
        oacc[1][ni] = mfma16(pf1, vf, oacc[1][ni]);
      }
    }
    __builtin_amdgcn_s_setprio(0);

    // ---- bottom barrier: DMA tile it+1 landed + my reads of tile it done ----
    if (it < 31)
      asm volatile("s_waitcnt vmcnt(0) lgkmcnt(0)\n\ts_barrier" ::: "memory");
  }

  // ---- epilogue: O / l ----
#pragma unroll
  for (int mi = 0; mi < 2; ++mi) {
    float inv[4];
#pragma unroll
    for (int r = 0; r < 4; ++r) inv[r] = 1.0f / __shfl(lrun[mi], quad * 4 + r);
    const size_t row0 = (size_t)(b * 2048 + qb * 128 + wave * 32 + mi * 16 + quad * 4);
#pragma unroll
    for (int ni = 0; ni < 8; ++ni) {
      const size_t base = row0 * 2048 + h * 128 + ni * 16 + l15;
#pragma unroll
      for (int r = 0; r < 4; ++r)
        Og[base + (size_t)r * 2048] = (bf16)(oacc[mi][ni][r] * inv[r]);
    }
  }
}

// ---------------------------------------------------------------------------
extern "C" void kernel_launch(void* const* d_in, const int* in_sizes, int n_in,
                              void* d_out, int out_size, void* d_ws, size_t ws_size,
                              hipStream_t stream) {
  (void)in_sizes; (void)n_in; (void)out_size; (void)ws_size;
  char* ws = (char*)d_ws;
  int*  flag   = (int*)ws;                    // [0,1024)
  bf16* x_c    = (bf16*)(ws + 1024);          // 16 MB; Og overlays (last x_c read
  bf16* Og     = x_c;                         //   is several dispatches earlier)
  bf16* WqkvT  = (bf16*)(ws + 16778240);      // [2304][2048] 9.4 MB
  bf16* WoT    = (bf16*)(ws + 26215424);      // [2048][2048] 8 MB
  bf16* bqkv   = (bf16*)(ws + 34604032);      // [2304]
  bf16* bo_c   = (bf16*)(ws + 34609152);      // [2048]
  bf16* Cqkv   = (bf16*)(ws + 34614272);      // [4096][2304] 18.9 MB -> 53488640
  bf16* VTg    = (bf16*)(ws + 53489664);      // [128][4096] 1 MB (kv-permuted)

  const dim3 blk(256);
  // dtype probe + bias conversion (one block)
  detect_bias_kernel<<<1, blk, 0, stream>>>(
      (const unsigned short*)d_in[0], flag, d_in[2], d_in[4], d_in[6], d_in[8],
      bqkv, bqkv + 2048, bqkv + 2176, bo_c);

  convertv_kernel<<<dim3(2048), blk, 0, stream>>>(d_in[0], x_c, (4096 * 2048) / 4, flag);
  // all four weight transposes in one dispatch
  convt4_kernel<<<dim3(68, 64, 2), blk, 0, stream>>>(
      d_in[1], d_in[7], d_in[3], d_in[5],
      WqkvT, WoT, WqkvT + 2048 * 2048, WqkvT + 2176 * 2048, flag);

  // QKV = x @ [Wq|Wk|Wv] + [bq|bk|bv] : [4096][2304]; V cols also written
  // to VTg in flash's kv-permuted layout (transv fused away)
  gemm_bt_kernel<<<dim3(18, 32), blk, 0, stream>>>(x_c, WqkvT, bqkv, Cqkv,
                                                   4096, 2304, 2048, 1, nullptr, VTg);
  // attention
  flash_kernel<<<dim3(16, 32), blk, 0, stream>>>(Cqkv, VTg, Og);
  // out = Og@Wo + bo (fp32 store per flag)
  gemm_bt_kernel<<<dim3(16, 32), blk, 0, stream>>>(Og, WoT, bo_c, d_out,
                                                   4096, 2048, 2048, 1, flag, nullptr);
}

// Round 13
// 302.441 us; speedup vs baseline: 1.2319x; 1.0242x over previous
//
#include <hip/hip_runtime.h>
#include <hip/hip_bf16.h>
#include <cstdint>

// Problem: B=2, S=2048, D=2048, HQ=16, DH=128, single shared K/V head (GQA).
// Inputs/outputs fp32 (runtime-detected; flag in ws[0]); compute bf16 MFMA.

typedef __bf16 bf16;
typedef __bf16 bf16x8 __attribute__((ext_vector_type(8)));
typedef __bf16 bf16x4 __attribute__((ext_vector_type(4)));
typedef float  floatx4 __attribute__((ext_vector_type(4)));

__device__ __forceinline__ floatx4 mfma16(bf16x8 a, bf16x8 b, floatx4 c) {
  return __builtin_amdgcn_mfma_f32_16x16x32_bf16(a, b, c, 0, 0, 0);
}

__device__ __forceinline__ void glds16(const bf16* g, bf16* l) {
  __builtin_amdgcn_global_load_lds(
      (const __attribute__((address_space(1))) unsigned int*)(const void*)g,
      (__attribute__((address_space(3))) unsigned int*)(void*)l, 16, 0, 0);
}

// ---------------------------------------------------------------------------
// dtype probe + bias convert in one dispatch (single block)
// ---------------------------------------------------------------------------
__global__ void detect_bias_kernel(
    const unsigned short* __restrict__ xs, int* flag,
    const void* s0, const void* s1, const void* s2, const void* s3,
    bf16* d0, bf16* d1, bf16* d2, bf16* d3) {
  __shared__ int cnt;
  if (threadIdx.x == 0) cnt = 0;
  __syncthreads();
  int bad = 0;
  for (int i = threadIdx.x; i < 8192; i += 256) {
    const unsigned e = (xs[i] >> 7) & 0xFF;
    if (e >= 0x90 || e <= 0x5F) bad++;
  }
  atomicAdd(&cnt, bad);
  __syncthreads();
  const int f = (cnt > 256) ? 1 : 0;
  if (threadIdx.x == 0) *flag = f;
  const void* ss[4] = {s0, s1, s2, s3};
  bf16* dd[4] = {d0, d1, d2, d3};
  const int nn[4] = {2048, 128, 128, 2048};
#pragma unroll
  for (int a = 0; a < 4; ++a)
    for (int i = threadIdx.x; i < nn[a]; i += 256)
      dd[a][i] = f ? (bf16)((const float*)ss[a])[i] : ((const bf16*)ss[a])[i];
}

// ---------------------------------------------------------------------------
// Round-13 prep_kernel: the four weight transposes AND the x conversion in
// ONE dispatch (was convt4 + convertv = 2 dispatches). All blocks depend only
// on *flag. grid (68,64,3): z=0,1 -> transposes (bx<64: Wq/Wo C=2048;
// bx>=64: Wk/Wv C=128; dst row stride 2048 for all four); z=2 -> x fp32/bf16
// -> bf16 conversion, grid-stride over n4 float4 groups.
// ---------------------------------------------------------------------------
__global__ __launch_bounds__(256) void prep_kernel(
    const void* __restrict__ sWq, const void* __restrict__ sWo,
    const void* __restrict__ sWk, const void* __restrict__ sWv,
    bf16* __restrict__ dWq, bf16* __restrict__ dWo,
    bf16* __restrict__ dWk, bf16* __restrict__ dWv,
    const void* __restrict__ xsrc, bf16* __restrict__ xdst, const int n4,
    const int* __restrict__ flag) {
  __shared__ bf16 tile[32][33];
  const int f = *flag;

  if (blockIdx.z == 2) {
    // ---- x conversion (old convertv), grid-stride over 68*64 blocks ----
    int i = (blockIdx.y * 68 + blockIdx.x) * 256 + threadIdx.x;
    const int stride = 68 * 64 * 256;
    if (f) {
      const float4* s = (const float4*)xsrc;
      for (; i < n4; i += stride) {
        const float4 v = s[i];
        bf16x4 o = {(bf16)v.x, (bf16)v.y, (bf16)v.z, (bf16)v.w};
        *(bf16x4*)(xdst + (size_t)i * 4) = o;
      }
    } else {
      const ushort4* s = (const ushort4*)xsrc;
      for (; i < n4; i += stride) ((ushort4*)xdst)[i] = s[i];
    }
    return;
  }

  // ---- weight transposes (old convt4) ----
  const int zz = blockIdx.z;
  const bool big = (blockIdx.x < 64);
  const void* src = big ? (zz ? sWo : sWq) : (zz ? sWv : sWk);
  bf16* dst       = big ? (zz ? dWo : dWq) : (zz ? dWv : dWk);
  const int C = big ? 2048 : 128;
  const int tx = threadIdx.x & 31, ty = threadIdx.x >> 5;
  const int bx = (big ? blockIdx.x : blockIdx.x - 64) * 32;
  const int by = blockIdx.y * 32;
  if (f) {
    const float* s = (const float*)src;
#pragma unroll
    for (int i = 0; i < 32; i += 8)
      tile[ty + i][tx] = (bf16)s[(size_t)(by + ty + i) * C + bx + tx];
  } else {
    const bf16* s = (const bf16*)src;
#pragma unroll
    for (int i = 0; i < 32; i += 8)
      tile[ty + i][tx] = s[(size_t)(by + ty + i) * C + bx + tx];
  }
  __syncthreads();
#pragma unroll
  for (int i = 0; i < 32; i += 8)
    dst[(size_t)(bx + ty + i) * 2048 + by + tx] = tile[tx][ty + i];
}

// ---------------------------------------------------------------------------
// C[M][N] = A[M][K] @ Bt[N][K]^T (+bias). m97 128x128 tile, BK=32, 4 waves.
// Round-9 config (measured best): __launch_bounds__(256,4) + bijective
// XCD-chunked swizzle. Round-10's explicit dbuf was flat (4-block overlap
// already hides the drain) — not re-applied.
// Round-12 fusion kept: optional V^T-permuted side-write (vtg != nullptr,
// gemm1 only). Blocks whose cols land in [2176,2304) also store their acc
// values to VTg in the flash kv-permuted layout: within a 32-row group,
// o=(mi&1)*16+quad*4+r -> perm position 8*quad+4*(mi&1)+r, one contiguous
// bf16x4 at VTg[(col-2176)*4096 + (row0&~31) + 8*quad + 4*(mi&1)].
// Bit-identical to the old transv pass. HW-verified round 12.
// ---------------------------------------------------------------------------
__global__ __launch_bounds__(256, 4) void gemm_bt_kernel(
    const bf16* __restrict__ A, const bf16* __restrict__ Bt,
    const bf16* __restrict__ bias, void* __restrict__ Cout,
    const int M, const int N, const int K, const int bias_mode,
    const int* __restrict__ f32out, bf16* __restrict__ vtg) {
  __shared__ __align__(16) bf16 ldsA[128 * 32];
  __shared__ __align__(16) bf16 ldsB[128 * 32];
  const int tid = threadIdx.x, lane = tid & 63, wave = tid >> 6;
  const int l15 = lane & 15, quad = lane >> 4;

  // XCD-chunked bijective swizzle (nwg % 8 == 0 for both call sites)
  const int nwg = gridDim.x * gridDim.y;
  int bid = blockIdx.y * gridDim.x + blockIdx.x;
  bid = (bid & 7) * (nwg >> 3) + (bid >> 3);
  const int m0 = (bid / gridDim.x) * 128, n0 = (bid % gridDim.x) * 128;

  const int wm = wave >> 1, wn = wave & 1;
  const int f32 = f32out ? *f32out : 0;

  floatx4 acc[4][4];
  const floatx4 z4 = {0.f, 0.f, 0.f, 0.f};
#pragma unroll
  for (int i = 0; i < 4; ++i)
#pragma unroll
    for (int j = 0; j < 4; ++j) acc[i][j] = z4;

  const int srow = (lane >> 2);
  const int scol = (lane & 3) * 8;

  for (int k0 = 0; k0 < K; k0 += 32) {
    __syncthreads();
#pragma unroll
    for (int j = 0; j < 2; ++j) {
      const int chunk = wave * 2 + j;
      glds16(A + (size_t)(m0 + chunk * 16 + srow) * K + k0 + scol, ldsA + chunk * 512);
      glds16(Bt + (size_t)(n0 + chunk * 16 + srow) * K + k0 + scol, ldsB + chunk * 512);
    }
    __syncthreads();
    bf16x8 af[4], bfr[4];
#pragma unroll
    for (int i = 0; i < 4; ++i) {
      af[i]  = *(const bf16x8*)(ldsA + (wm * 64 + i * 16 + l15) * 32 + quad * 8);
      bfr[i] = *(const bf16x8*)(ldsB + (wn * 64 + i * 16 + l15) * 32 + quad * 8);
    }
#pragma unroll
    for (int mi = 0; mi < 4; ++mi)
#pragma unroll
      for (int ni = 0; ni < 4; ++ni)
        acc[mi][ni] = mfma16(af[mi], bfr[ni], acc[mi][ni]);
  }

#pragma unroll
  for (int mi = 0; mi < 4; ++mi) {
    const int row0 = m0 + wm * 64 + mi * 16 + quad * 4;
#pragma unroll
    for (int ni = 0; ni < 4; ++ni) {
      const int col = n0 + wn * 64 + ni * 16 + l15;
      const float badd = (bias_mode == 1) ? (float)bias[col] : 0.f;
      bf16x4 v4;
#pragma unroll
      for (int r = 0; r < 4; ++r) {
        float v = acc[mi][ni][r] + badd;
        if (bias_mode == 2) v += (float)bias[row0 + r];
        const size_t idx = (size_t)(row0 + r) * N + col;
        if (f32) ((float*)Cout)[idx] = v;
        else     ((bf16*)Cout)[idx]  = (bf16)v;
        v4[r] = (bf16)v;
      }
      if (vtg && col >= 2176)
        *(bf16x4*)(vtg + (size_t)(col - 2176) * 4096 + (row0 & ~31) +
                   8 * quad + 4 * (mi & 1)) = v4;
    }
  }
}

// ---------------------------------------------------------------------------
// Flash attention v11 — measured plateau: 79.3-80.0us, MfmaUtil 36-37,
// bank conflicts 0, VGPR 92. Closed fronts: global-direct V hits the L2
// request-rate wall (v5, v12: 140us); more waves re-saturate the LDS pipe
// (v7); K-frags in registers spill (v8). Structure: K+VT double-buffered in
// LDS via global_load_lds DMA (linear dest, XOR-swizzled per-lane global
// source, m173); in-register P via permuted-kv (v10); one
// vmcnt(0)+lgkm(0)+barrier per iteration.
// ---------------------------------------------------------------------------
__global__ __launch_bounds__(256, 2) void flash_kernel(
    const bf16* __restrict__ Cqkv,  // [4096][2304]  Q cols 0..2047, K cols 2048..2175
    const bf16* __restrict__ VTg,   // [128][4096] kv-permuted
    bf16* __restrict__ Og) {        // [4096][2048]
  __shared__ __align__(16) bf16 lds_all[32768];  // 64 KB
  bf16* ldsK  = lds_all;           // [2][64 kv][128 d], granule slot = g ^ (row&15)
  bf16* ldsVT = lds_all + 16384;   // [2][128 d][64 kv'], granule slot = g ^ (d&7)

  const int tid = threadIdx.x, lane = tid & 63, wave = tid >> 6;
  const int l15 = lane & 15, quad = lane >> 4;
  const int qb = blockIdx.x, bh = blockIdx.y;
  const int b = bh >> 4, h = bh & 15;

  // ---- Q fragments direct from global (one-time; B-op: n=l15, k=quad*8+j) ----
  bf16x8 qfrag[2][4];
  {
    const bf16* qbase = Cqkv + (size_t)(b * 2048 + qb * 128 + wave * 32) * 2304 + h * 128;
#pragma unroll
    for (int qi = 0; qi < 2; ++qi)
#pragma unroll
      for (int kf = 0; kf < 4; ++kf)
        qfrag[qi][kf] =
            *(const bf16x8*)(qbase + (size_t)(qi * 16 + l15) * 2304 + kf * 32 + quad * 8);
  }

  const bf16* kb  = Cqkv + 2048 + (size_t)(b * 2048) * 2304;
  const bf16* vtb = VTg + (size_t)b * 2048;

  // staging geometry: 16 K-chunks + 16 VT-chunks (1 KB each), wave DMAs 4+4.
  int rK[4], gK[4], dV[4], gV[4];
#pragma unroll
  for (int j = 0; j < 4; ++j) {
    const int c = wave * 4 + j;
    rK[j] = c * 4 + quad;          gK[j] = l15 ^ (rK[j] & 15);
    dV[j] = c * 8 + (lane >> 3);   gV[j] = (lane & 7) ^ (dV[j] & 7);
  }

  // ---- prologue: DMA tile 0 into buffer 0, publish ----
#pragma unroll
  for (int j = 0; j < 4; ++j) {
    const int c = wave * 4 + j;
    glds16(kb + (size_t)rK[j] * 2304 + gK[j] * 8, ldsK + c * 512);
    glds16(vtb + (size_t)dV[j] * 4096 + gV[j] * 8, ldsVT + c * 512);
  }
  asm volatile("s_waitcnt vmcnt(0)\n\ts_barrier" ::: "memory");

  floatx4 oacc[2][8];
  const floatx4 z4 = {0.f, 0.f, 0.f, 0.f};
#pragma unroll
  for (int mi = 0; mi < 2; ++mi)
#pragma unroll
    for (int ni = 0; ni < 8; ++ni) oacc[mi][ni] = z4;
  float lrun[2] = {0.f, 0.f};
  const float c1  = 0.12751745f;  // (1/sqrt(128)) * log2(e)
  const float mu2 = 4.3280850f;   // 3 * log2(e)

  for (int it = 0; it < 32; ++it) {
    const bf16* kcur  = ldsK  + (it & 1) * 8192;
    const bf16* vtcur = ldsVT + (it & 1) * 8192;

    // ---- DMA tile it+1 into the other buffers at iter TOP ----
    if (it < 31) {
      const int kvn = (it + 1) * 64;
      bf16* knext  = ldsK  + ((it + 1) & 1) * 8192;
      bf16* vtnext = ldsVT + ((it + 1) & 1) * 8192;
#pragma unroll
      for (int j = 0; j < 4; ++j) {
        const int c = wave * 4 + j;
        glds16(kb + (size_t)(kvn + rK[j]) * 2304 + gK[j] * 8, knext + c * 512);
        glds16(vtb + (size_t)dV[j] * 4096 + kvn + gV[j] * 8, vtnext + c * 512);
      }
    }

    // ---- S^T = K.Q^T : D[m=kv 64][n=q 16] x2 qi; af reused across qi ----
    floatx4 sacc[4][2];
#pragma unroll
    for (int kvi = 0; kvi < 4; ++kvi) { sacc[kvi][0] = z4; sacc[kvi][1] = z4; }
    __builtin_amdgcn_s_setprio(1);
#pragma unroll
    for (int kf = 0; kf < 4; ++kf) {
      const int gg = (kf * 4 + quad) ^ l15;
#pragma unroll
      for (int kvi = 0; kvi < 4; ++kvi) {
        bf16x8 af = *(const bf16x8*)(kcur + (kvi * 16 + l15) * 128 + gg * 8);
        sacc[kvi][0] = mfma16(af, qfrag[0][kf], sacc[kvi][0]);
        sacc[kvi][1] = mfma16(af, qfrag[1][kf], sacc[kvi][1]);
      }
    }
    __builtin_amdgcn_s_setprio(0);

    // ---- P = exp2(s*c1 - mu2): bf16x4 per (qi,kvi), kept in REGISTERS ----
    bf16x4 pv[2][4];
    float rs[2] = {0.f, 0.f};
#pragma unroll
    for (int qi = 0; qi < 2; ++qi) {
#pragma unroll
      for (int kvi = 0; kvi < 4; ++kvi) {
#pragma unroll
        for (int r = 0; r < 4; ++r) {
          const float p = __builtin_amdgcn_exp2f(fmaf(sacc[kvi][qi][r], c1, -mu2));
          rs[qi] += p;
          pv[qi][kvi][r] = (bf16)p;
        }
      }
    }
#pragma unroll
    for (int qi = 0; qi < 2; ++qi) {
      float r2 = rs[qi];
      r2 += __shfl_xor(r2, 16);
      r2 += __shfl_xor(r2, 32);
      lrun[qi] += r2;
    }

    // ---- O += P.V ; P lane-local, V stored permuted -> single b128 reads ----
    __builtin_amdgcn_s_setprio(1);
#pragma unroll
    for (int kf2 = 0; kf2 < 2; ++kf2) {
      const bf16x8 pf0 = __builtin_shufflevector(pv[0][kf2 * 2], pv[0][kf2 * 2 + 1],
                                                 0, 1, 2, 3, 4, 5, 6, 7);
      const bf16x8 pf1 = __builtin_shufflevector(pv[1][kf2 * 2], pv[1][kf2 * 2 + 1],
                                                 0, 1, 2, 3, 4, 5, 6, 7);
      const int gp = kf2 * 4 + quad;  // granule of permuted kv' = 32*kf2+8*quad
#pragma unroll
      for (int ni = 0; ni < 8; ++ni) {
        const int d = ni * 16 + l15;
        const bf16x8 vf =
            *(const bf16x8*)(vtcur + d * 64 + ((gp ^ (l15 & 7)) << 3));
        oacc[0][ni] = mfma16(pf0, vf, oacc[0][ni]);
        oacc[1][ni] = mfma16(pf1, vf, oacc[1][ni]);
      }
    }
    __builtin_amdgcn_s_setprio(0);

    // ---- bottom barrier: DMA tile it+1 landed + my reads of tile it done ----
    if (it < 31)
      asm volatile("s_waitcnt vmcnt(0) lgkmcnt(0)\n\ts_barrier" ::: "memory");
  }

  // ---- epilogue: O / l ----
#pragma unroll
  for (int mi = 0; mi < 2; ++mi) {
    float inv[4];
#pragma unroll
    for (int r = 0; r < 4; ++r) inv[r] = 1.0f / __shfl(lrun[mi], quad * 4 + r);
    const size_t row0 = (size_t)(b * 2048 + qb * 128 + wave * 32 + mi * 16 + quad * 4);
#pragma unroll
    for (int ni = 0; ni < 8; ++ni) {
      const size_t base = row0 * 2048 + h * 128 + ni * 16 + l15;
#pragma unroll
      for (int r = 0; r < 4; ++r)
        Og[base + (size_t)r * 2048] = (bf16)(oacc[mi][ni][r] * inv[r]);
    }
  }
}

// ---------------------------------------------------------------------------
extern "C" void kernel_launch(void* const* d_in, const int* in_sizes, int n_in,
                              void* d_out, int out_size, void* d_ws, size_t ws_size,
                              hipStream_t stream) {
  (void)in_sizes; (void)n_in; (void)out_size; (void)ws_size;
  char* ws = (char*)d_ws;
  int*  flag   = (int*)ws;                    // [0,1024)
  bf16* x_c    = (bf16*)(ws + 1024);          // 16 MB; Og overlays (last x_c read
  bf16* Og     = x_c;                         //   is several dispatches earlier)
  bf16* WqkvT  = (bf16*)(ws + 16778240);      // [2304][2048] 9.4 MB
  bf16* WoT    = (bf16*)(ws + 26215424);      // [2048][2048] 8 MB
  bf16* bqkv   = (bf16*)(ws + 34604032);      // [2304]
  bf16* bo_c   = (bf16*)(ws + 34609152);      // [2048]
  bf16* Cqkv   = (bf16*)(ws + 34614272);      // [4096][2304] 18.9 MB -> 53488640
  bf16* VTg    = (bf16*)(ws + 53489664);      // [128][4096] 1 MB (kv-permuted)

  const dim3 blk(256);
  // dtype probe + bias conversion (one block)
  detect_bias_kernel<<<1, blk, 0, stream>>>(
      (const unsigned short*)d_in[0], flag, d_in[2], d_in[4], d_in[6], d_in[8],
      bqkv, bqkv + 2048, bqkv + 2176, bo_c);

  // all four weight transposes + x conversion in ONE dispatch
  prep_kernel<<<dim3(68, 64, 3), blk, 0, stream>>>(
      d_in[1], d_in[7], d_in[3], d_in[5],
      WqkvT, WoT, WqkvT + 2048 * 2048, WqkvT + 2176 * 2048,
      d_in[0], x_c, (4096 * 2048) / 4, flag);

  // QKV = x @ [Wq|Wk|Wv] + [bq|bk|bv] : [4096][2304]; V cols also written
  // to VTg in flash's kv-permuted layout (transv fused away)
  gemm_bt_kernel<<<dim3(18, 32), blk, 0, stream>>>(x_c, WqkvT, bqkv, Cqkv,
                                                   4096, 2304, 2048, 1, nullptr, VTg);
  // attention
  flash_kernel<<<dim3(16, 32), blk, 0, stream>>>(Cqkv, VTg, Og);
  // out = Og@Wo + bo (fp32 store per flag)
  gemm_bt_kernel<<<dim3(16, 32), blk, 0, stream>>>(Og, WoT, bo_c, d_out,
                                                   4096, 2048, 2048, 1, flag, nullptr);
}